// Round 12
// baseline (52.126 us; speedup 1.0000x reference)
//
#include <hip/hip_runtime.h>
#include <hip/hip_bf16.h>

#define BATCH 512
#define SEQL  512
#define VOCAB 100000
#define NCH   14
#define NCLS  5

// contrib row: 64 bf16 = 128 B = ONE cache line per token gather.
// tap-segment j at bf16-index SIDX[j]: SIDX={0,16,32,44,53}, cstart={0,0,2,5,9}
// each segment covered by uint4 pair at 16B-block B0[j]={0,2,4,5,6}.

#define BIAS_OFF    0        // f32[16]
#define CONTRIB_OFF 128      // bf16 [100000][64] = 12.8 MB

typedef __attribute__((ext_vector_type(8))) short bf16x8;
typedef __attribute__((ext_vector_type(4))) float f32x4;

static __device__ __forceinline__ unsigned short bf16bits(float f) {
    __hip_bfloat16 h = __float2bfloat16(f);
    return __builtin_bit_cast(unsigned short, h);
}
static __device__ __forceinline__ float bf16f(unsigned int hbits) {
    union { unsigned int u; float f; } x; x.u = hbits << 16; return x.f;
}
static __device__ __forceinline__ unsigned int getdw(const uint4& u, int w) {
    switch (w) { case 0: return u.x; case 1: return u.y; case 2: return u.z; default: return u.w; }
}

// ---------------- contrib GEMM with fused weight repack:
// [100k,128]x[128,64] bf16 MFMA. One 64-row tile per block (grid 1563);
// inter-block TLP provides the pipelining (4 blocks/CU resident).
// Prologue: stage raw conv weights into LDS, compute this thread's 16
// B-fragments in registers (replaces the separate repack_w kernel).
__global__ __launch_bounds__(256, 4) void contrib_gemm(
    const float* __restrict__ emb,
    const float* __restrict__ w2, const float* __restrict__ b2,
    const float* __restrict__ w3, const float* __restrict__ b3,
    const float* __restrict__ w4, const float* __restrict__ b4,
    const float* __restrict__ w5, const float* __restrict__ b5,
    float* __restrict__ biasf,
    unsigned short* __restrict__ contrib)
{
    __shared__ float wraw[5400];                 // w2|w3|w4|w5 concatenated
    __shared__ unsigned short xs[64 * 128];      // 16 KB, XOR-swizzled bf16

    const int v0  = blockIdx.x * 64;
    const int tid = threadIdx.x;
    const int l   = tid & 63;
    const int wt  = tid >> 6;

    // bias -> ws (block 0 only; consumed by gather kernel, stream-ordered)
    if (blockIdx.x == 0 && tid < 16) {
        float bv = 0.f;
        if (tid < 2)        bv = b2[tid];
        else if (tid < 5)   bv = b3[tid - 2];
        else if (tid < 9)   bv = b4[tid - 5];
        else if (tid < NCH) bv = b5[tid - 9];
        biasf[tid] = bv;
    }

    // ---- stage raw weights -> LDS (coalesced; L2-hot after first blocks) ----
    for (int i = tid; i < 400;  i += 256) wraw[i]        = w2[i];
    for (int i = tid; i < 900;  i += 256) wraw[400 + i]  = w3[i];
    for (int i = tid; i < 1600; i += 256) wraw[1300 + i] = w4[i];
    for (int i = tid; i < 2500; i += 256) wraw[2900 + i] = w5[i];
    __syncthreads();

    // ---- compute this thread's 16 B-fragments (same math as old repack_w) ----
    // B[k=d][n]: lane l holds n = nt*16 + (l&15), d = ks*32 + (l>>4)*8 + e.
    bf16x8 bfrag[16];
    const int nbase = l & 15;
    const int dbase = (l >> 4) << 3;
    #pragma unroll
    for (int nt = 0; nt < 4; ++nt) {
        const int n = nt * 16 + nbase;
        int j = -1, c = 0;
        if (n < 14)                 { j = 0; c = n; }
        else if (n >= 16 && n < 30) { j = 1; c = n - 16; }
        else if (n >= 32 && n < 44) { j = 2; c = n - 30; }
        else if (n >= 44 && n < 53) { j = 3; c = n - 39; }
        else if (n >= 53 && n < 58) { j = 4; c = n - 44; }
        int kc = 2, wb = 0;
        if (j >= 0) {
            kc = 2 + (c >= 2) + (c >= 5) + (c >= 9);
            const int grp = (c >= 2) + (c >= 5) + (c >= 9);
            const int ob  = (grp == 0) ? 0 : (grp == 1) ? 2 : (grp == 2) ? 5 : 9;
            const int wbase = (grp == 0) ? 0 : (grp == 1) ? 400 : (grp == 2) ? 1300 : 2900;
            wb = wbase + (c - ob) * 100 * kc + j;
        }
        #pragma unroll
        for (int ks = 0; ks < 4; ++ks) {
            bf16x8 s;
            #pragma unroll
            for (int e = 0; e < 8; ++e) {
                const int d = ks * 32 + dbase + e;
                float v = 0.f;
                if (j >= 0 && d < 100) v = wraw[wb + d * kc];
                s[e] = (short)bf16bits(v);
            }
            bfrag[nt * 4 + ks] = s;
        }
    }

    // ---- stage 64 emb rows (coalesced stream) -> swizzled bf16 LDS ----
    const float4* __restrict__ emb4 = reinterpret_cast<const float4*>(emb);
    uint2* xs2 = reinterpret_cast<uint2*>(xs);
    #pragma unroll
    for (int it = 0; it < 8; ++it) {
        const int i = tid + it * 256;
        const int r = i >> 5;
        const int q = i & 31;
        const int v = v0 + r;
        uint lo = 0, hi = 0;
        if (v < VOCAB && q < 25) {
            float4 x = emb4[(long)v * 25 + q];
            lo = (uint)bf16bits(x.x) | ((uint)bf16bits(x.y) << 16);
            hi = (uint)bf16bits(x.z) | ((uint)bf16bits(x.w) << 16);
        }
        const int addr = (r * 256 + q * 8) ^ ((r & 7) << 4);
        xs2[addr >> 3] = make_uint2(lo, hi);
    }
    __syncthreads();

    // ---- MFMA: wave computes 16 rows x 64 cols, K=128 ----
    f32x4 acc[4] = {{0.f,0.f,0.f,0.f},{0.f,0.f,0.f,0.f},
                    {0.f,0.f,0.f,0.f},{0.f,0.f,0.f,0.f}};
    const char* xsb = reinterpret_cast<const char*>(xs);
    const int arow = wt * 16 + (l & 15);
    #pragma unroll
    for (int ks = 0; ks < 4; ++ks) {
        const int aad = (arow * 256 + (ks * 32 + dbase) * 2) ^ ((arow & 7) << 4);
        bf16x8 a = *reinterpret_cast<const bf16x8*>(xsb + aad);
        #pragma unroll
        for (int nt = 0; nt < 4; ++nt)
            acc[nt] = __builtin_amdgcn_mfma_f32_16x16x32_bf16(
                a, bfrag[nt * 4 + ks], acc[nt], 0, 0, 0);
    }

    // C: row = (l>>4)*4 + r, col = nt*16 + (l&15); write bf16 contrib rows
    const int vbase = v0 + wt * 16 + ((l >> 4) << 2);
    #pragma unroll
    for (int nt = 0; nt < 4; ++nt) {
        #pragma unroll
        for (int r = 0; r < 4; ++r) {
            const int v = vbase + r;
            if (v < VOCAB)
                contrib[(long)v * 64 + nt * 16 + (l & 15)] = bf16bits(acc[nt][r]);
        }
    }
}

// ---------------- gather + conv-sum + relu + max + FC, one block per batch row
// (R9 version: 2 aligned uint4 per tap segment, 1 line per row touch)
__global__ __launch_bounds__(512, 4) void gather_max_fc(
    const int* __restrict__ words,
    const unsigned short* __restrict__ contrib,
    const float* __restrict__ biasf,
    const float* __restrict__ fcw, const float* __restrict__ fcb,
    float* __restrict__ out)
{
    __shared__ float red[8][NCH];
    __shared__ float sfin[NCH];

    const int b  = blockIdx.x;
    const int t  = threadIdx.x;
    const int l  = t & 63;
    const int wv = t >> 6;

    constexpr int KC[NCH]  = {2,2, 3,3,3, 4,4,4,4, 5,5,5,5,5};
    constexpr int SIDX[5]  = {0,16,32,44,53};
    constexpr int CST[5]   = {0,0,2,5,9};
    constexpr int B0[5]    = {0,2,4,5,6};

    // token indices (clamped; out-of-range taps masked later)
    int tok[5];
    #pragma unroll
    for (int j = 0; j < 5; ++j) {
        int u = t + j; if (u > SEQL - 1) u = SEQL - 1;
        tok[j] = words[b * SEQL + u];
    }

    // one-line-per-row gathers: 2 aligned uint4 per tap segment
    uint4 u0[5], u1[5];
    #pragma unroll
    for (int j = 0; j < 5; ++j) {
        const uint4* rp = reinterpret_cast<const uint4*>(contrib + (long)tok[j] * 64);
        u0[j] = rp[B0[j]];
        u1[j] = rp[B0[j] + 1];
    }

    // y[c] = sum_j contrib[tok[t+j]][(j,c)]  (all indices compile-time)
    float y[NCH];
    #pragma unroll
    for (int c = 0; c < NCH; ++c) {
        float s = 0.f;
        #pragma unroll
        for (int j = 0; j < 5; ++j) {
            if (j < KC[c]) {
                const int n   = SIDX[j] + (c - CST[j]);
                const int rel = 2 * n - 16 * B0[j];
                const int w   = rel >> 2;
                const int h   = (rel >> 1) & 1;
                const unsigned int dw = (w < 4) ? getdw(u0[j], w) : getdw(u1[j], w - 4);
                s += bf16f(h ? (dw >> 16) : (dw & 0xffffu));
            }
        }
        y[c] = s;
    }

    // bias + relu + validity mask + 64-lane max + cross-wave max
    #pragma unroll
    for (int c = 0; c < NCH; ++c) {
        float v = 0.f;
        if (t + KC[c] <= SEQL) v = fmaxf(y[c] + biasf[c], 0.f);
        #pragma unroll
        for (int off = 32; off > 0; off >>= 1)
            v = fmaxf(v, __shfl_xor(v, off, 64));
        if (l == 0) red[wv][c] = v;
    }
    __syncthreads();
    if (t < NCH) {
        float f = red[0][t];
        #pragma unroll
        for (int w = 1; w < 8; ++w) f = fmaxf(f, red[w][t]);
        sfin[t] = f;
    }
    __syncthreads();
    if (t < NCLS) {
        float acc = fcb[t];
        #pragma unroll
        for (int o = 0; o < NCH; ++o) acc += fcw[t * NCH + o] * sfin[o];
        out[b * NCLS + t] = acc;
    }
}

extern "C" void kernel_launch(void* const* d_in, const int* in_sizes, int n_in,
                              void* d_out, int out_size, void* d_ws, size_t ws_size,
                              hipStream_t stream) {
    const int*   words = (const int*)  d_in[0];
    const float* emb   = (const float*)d_in[1];
    const float* w2    = (const float*)d_in[2];
    const float* b2    = (const float*)d_in[3];
    const float* w3    = (const float*)d_in[4];
    const float* b3    = (const float*)d_in[5];
    const float* w4    = (const float*)d_in[6];
    const float* b4    = (const float*)d_in[7];
    const float* w5    = (const float*)d_in[8];
    const float* b5    = (const float*)d_in[9];
    const float* fcw   = (const float*)d_in[10];
    const float* fcb   = (const float*)d_in[11];
    float* out = (float*)d_out;
    char*  ws  = (char*)d_ws;

    float*          biasf   = (float*)(ws + BIAS_OFF);
    unsigned short* contrib = (unsigned short*)(ws + CONTRIB_OFF);

    hipLaunchKernelGGL(contrib_gemm, dim3((VOCAB + 63) / 64), dim3(256), 0, stream,
                       emb, w2, b2, w3, b3, w4, b4, w5, b5, biasf, contrib);
    hipLaunchKernelGGL(gather_max_fc, dim3(BATCH), dim3(512), 0, stream,
                       words, contrib, biasf, fcw, fcb, out);
}

// Round 13
// 34.804 us; speedup vs baseline: 1.4977x; 1.4977x over previous
//
#include <hip/hip_runtime.h>
#include <hip/hip_bf16.h>

#define BATCH 512
#define SEQL  512
#define VOCAB 100000
#define NCH   14
#define NCLS  5

// contrib row: 64 bf16 = 128 B = ONE cache line per token gather.
// tap-segment j at bf16-index SIDX[j]: SIDX={0,16,32,44,53}, cstart={0,0,2,5,9}
// each segment covered by uint4 pair at 16B-block B0[j]={0,2,4,5,6}.

#define WSB_OFF     0        // B-frags: 4nt*4ks*64l*8e bf16 = 16384 B
#define BIAS_OFF    16384    // f32[16]
#define CONTRIB_OFF 32768    // bf16 [100000][64] = 12.8 MB

typedef __attribute__((ext_vector_type(8))) short bf16x8;
typedef __attribute__((ext_vector_type(4))) float f32x4;

static __device__ __forceinline__ unsigned short bf16bits(float f) {
    __hip_bfloat16 h = __float2bfloat16(f);
    return __builtin_bit_cast(unsigned short, h);
}
static __device__ __forceinline__ float bf16f(unsigned int hbits) {
    union { unsigned int u; float f; } x; x.u = hbits << 16; return x.f;
}
static __device__ __forceinline__ unsigned int getdw(const uint4& u, int w) {
    switch (w) { case 0: return u.x; case 1: return u.y; case 2: return u.z; default: return u.w; }
}

// ---------------- repack: conv weights -> B-fragments for the contrib GEMM
__global__ void repack_w(
    const float* __restrict__ w2, const float* __restrict__ b2,
    const float* __restrict__ w3, const float* __restrict__ b3,
    const float* __restrict__ w4, const float* __restrict__ b4,
    const float* __restrict__ w5, const float* __restrict__ b5,
    unsigned short* __restrict__ wsb, float* __restrict__ biasf)
{
    const float* WP[4] = {w2, w3, w4, w5};
    const int gi = blockIdx.x * 256 + threadIdx.x;
    if (gi < 8192) {
        int nt = gi >> 11;
        int ks = (gi >> 9) & 3;
        int l  = (gi >> 3) & 63;
        int e  = gi & 7;
        int n  = nt * 16 + (l & 15);
        int k  = ks * 32 + ((l >> 4) << 3) + e;    // = emb dim d
        int j = -1, c = 0;
        if (n < 14)                 { j = 0; c = n; }
        else if (n >= 16 && n < 30) { j = 1; c = n - 16; }
        else if (n >= 32 && n < 44) { j = 2; c = 2 + (n - 32); }
        else if (n >= 44 && n < 53) { j = 3; c = 5 + (n - 44); }
        else if (n >= 53 && n < 58) { j = 4; c = 9 + (n - 53); }
        float v = 0.f;
        if (j >= 0 && k < 100) {
            int kc  = 2 + (c >= 2) + (c >= 5) + (c >= 9);
            int grp = (c >= 2) + (c >= 5) + (c >= 9);
            int ob  = (grp == 0) ? 0 : (grp == 1) ? 2 : (grp == 2) ? 5 : 9;
            v = WP[grp][((c - ob) * 100 + k) * kc + j];
        }
        wsb[gi] = bf16bits(v);
    }
    if (blockIdx.x == 0 && threadIdx.x < 16) {
        const int t = threadIdx.x;
        float bv = 0.f;
        if (t < 2)        bv = b2[t];
        else if (t < 5)   bv = b3[t - 2];
        else if (t < 9)   bv = b4[t - 5];
        else if (t < NCH) bv = b5[t - 9];
        biasf[t] = bv;
    }
}

// ---------------- contrib GEMM: [100k,128]x[128,64] bf16 MFMA, coalesced stream
// One 64-row tile per block (grid 1563, 4 blocks/CU); inter-block TLP pipelines
// staging of block n+1 under MFMA/write of block n (m114). Regular stores keep
// contrib L2-resident for the gather kernel.
__global__ __launch_bounds__(256, 4) void contrib_gemm(
    const float* __restrict__ emb,
    const char* __restrict__ ws,
    unsigned short* __restrict__ contrib)
{
    __shared__ unsigned short xs[64 * 128];   // 16 KB, XOR-swizzled bf16
    const int v0  = blockIdx.x * 64;
    const int tid = threadIdx.x;
    const int l   = tid & 63;
    const int wt  = tid >> 6;

    const float4* __restrict__ emb4 = reinterpret_cast<const float4*>(emb);
    uint2* xs2 = reinterpret_cast<uint2*>(xs);
    #pragma unroll
    for (int it = 0; it < 8; ++it) {
        const int i = tid + it * 256;
        const int r = i >> 5;
        const int q = i & 31;
        const int v = v0 + r;
        uint lo = 0, hi = 0;
        if (v < VOCAB && q < 25) {
            float4 x = emb4[(long)v * 25 + q];
            lo = (uint)bf16bits(x.x) | ((uint)bf16bits(x.y) << 16);
            hi = (uint)bf16bits(x.z) | ((uint)bf16bits(x.w) << 16);
        }
        const int addr = (r * 256 + q * 8) ^ ((r & 7) << 4);
        xs2[addr >> 3] = make_uint2(lo, hi);
    }
    __syncthreads();

    f32x4 acc[4] = {{0.f,0.f,0.f,0.f},{0.f,0.f,0.f,0.f},
                    {0.f,0.f,0.f,0.f},{0.f,0.f,0.f,0.f}};
    const char* xsb = reinterpret_cast<const char*>(xs);
    const int arow = wt * 16 + (l & 15);
    const int dl   = (l >> 4) << 3;
    #pragma unroll
    for (int ks = 0; ks < 4; ++ks) {
        const int aad = (arow * 256 + (ks * 32 + dl) * 2) ^ ((arow & 7) << 4);
        bf16x8 a = *reinterpret_cast<const bf16x8*>(xsb + aad);
        #pragma unroll
        for (int nt = 0; nt < 4; ++nt) {
            bf16x8 bf = *reinterpret_cast<const bf16x8*>(
                ws + WSB_OFF + ((nt * 4 + ks) * 64 + l) * 16);
            acc[nt] = __builtin_amdgcn_mfma_f32_16x16x32_bf16(a, bf, acc[nt], 0, 0, 0);
        }
    }

    const int vbase = v0 + wt * 16 + ((l >> 4) << 2);
    #pragma unroll
    for (int nt = 0; nt < 4; ++nt) {
        #pragma unroll
        for (int r = 0; r < 4; ++r) {
            const int v = vbase + r;
            if (v < VOCAB)
                contrib[(long)v * 64 + nt * 16 + (l & 15)] = bf16bits(acc[nt][r]);
        }
    }
}

// ---------------- gather + conv-sum + relu + max + FC, one block per batch row
__global__ __launch_bounds__(512, 4) void gather_max_fc(
    const int* __restrict__ words,
    const unsigned short* __restrict__ contrib,
    const float* __restrict__ biasf,
    const float* __restrict__ fcw, const float* __restrict__ fcb,
    float* __restrict__ out)
{
    __shared__ float red[8][NCH];
    __shared__ float sfin[NCH];

    const int b  = blockIdx.x;
    const int t  = threadIdx.x;
    const int l  = t & 63;
    const int wv = t >> 6;

    constexpr int KC[NCH]  = {2,2, 3,3,3, 4,4,4,4, 5,5,5,5,5};
    constexpr int SIDX[5]  = {0,16,32,44,53};
    constexpr int CST[5]   = {0,0,2,5,9};
    constexpr int B0[5]    = {0,2,4,5,6};

    // token indices (clamped; out-of-range taps masked later)
    int tok[5];
    #pragma unroll
    for (int j = 0; j < 5; ++j) {
        int u = t + j; if (u > SEQL - 1) u = SEQL - 1;
        tok[j] = words[b * SEQL + u];
    }

    // one-line-per-row gathers: 2 aligned uint4 per tap segment
    uint4 u0[5], u1[5];
    #pragma unroll
    for (int j = 0; j < 5; ++j) {
        const uint4* rp = reinterpret_cast<const uint4*>(contrib + (long)tok[j] * 64);
        u0[j] = rp[B0[j]];
        u1[j] = rp[B0[j] + 1];
    }

    // y[c] = sum_j contrib[tok[t+j]][(j,c)]  (all indices compile-time)
    float y[NCH];
    #pragma unroll
    for (int c = 0; c < NCH; ++c) {
        float s = 0.f;
        #pragma unroll
        for (int j = 0; j < 5; ++j) {
            if (j < KC[c]) {
                const int n   = SIDX[j] + (c - CST[j]);
                const int rel = 2 * n - 16 * B0[j];
                const int w   = rel >> 2;
                const int h   = (rel >> 1) & 1;
                const unsigned int dw = (w < 4) ? getdw(u0[j], w) : getdw(u1[j], w - 4);
                s += bf16f(h ? (dw >> 16) : (dw & 0xffffu));
            }
        }
        y[c] = s;
    }

    // bias + relu + validity mask + 64-lane max + cross-wave max
    #pragma unroll
    for (int c = 0; c < NCH; ++c) {
        float v = 0.f;
        if (t + KC[c] <= SEQL) v = fmaxf(y[c] + biasf[c], 0.f);
        #pragma unroll
        for (int off = 32; off > 0; off >>= 1)
            v = fmaxf(v, __shfl_xor(v, off, 64));
        if (l == 0) red[wv][c] = v;
    }
    __syncthreads();
    if (t < NCH) {
        float f = red[0][t];
        #pragma unroll
        for (int w = 1; w < 8; ++w) f = fmaxf(f, red[w][t]);
        sfin[t] = f;
    }
    __syncthreads();
    if (t < NCLS) {
        float acc = fcb[t];
        #pragma unroll
        for (int o = 0; o < NCH; ++o) acc += fcw[t * NCH + o] * sfin[o];
        out[b * NCLS + t] = acc;
    }
}

extern "C" void kernel_launch(void* const* d_in, const int* in_sizes, int n_in,
                              void* d_out, int out_size, void* d_ws, size_t ws_size,
                              hipStream_t stream) {
    const int*   words = (const int*)  d_in[0];
    const float* emb   = (const float*)d_in[1];
    const float* w2    = (const float*)d_in[2];
    const float* b2    = (const float*)d_in[3];
    const float* w3    = (const float*)d_in[4];
    const float* b3    = (const float*)d_in[5];
    const float* w4    = (const float*)d_in[6];
    const float* b4    = (const float*)d_in[7];
    const float* w5    = (const float*)d_in[8];
    const float* b5    = (const float*)d_in[9];
    const float* fcw   = (const float*)d_in[10];
    const float* fcb   = (const float*)d_in[11];
    float* out = (float*)d_out;
    char*  ws  = (char*)d_ws;

    unsigned short* wsb     = (unsigned short*)(ws + WSB_OFF);
    float*          biasf   = (float*)(ws + BIAS_OFF);
    unsigned short* contrib = (unsigned short*)(ws + CONTRIB_OFF);

    hipLaunchKernelGGL(repack_w, dim3(32), dim3(256), 0, stream,
                       w2, b2, w3, b3, w4, b4, w5, b5, wsb, biasf);
    hipLaunchKernelGGL(contrib_gemm, dim3((VOCAB + 63) / 64), dim3(256), 0, stream,
                       emb, ws, contrib);
    hipLaunchKernelGGL(gather_max_fc, dim3(BATCH), dim3(512), 0, stream,
                       words, contrib, biasf, fcw, fcb, out);
}